// Round 2
// baseline (687.593 us; speedup 1.0000x reference)
//
#include <hip/hip_runtime.h>

#define NHEADS 16
#define HD 128
#define LSEQ 2048
#define NBATCH 2
#define HDIM 2048
#define NQKV 6144
#define SCALE 0.08838834764831845f

typedef __attribute__((ext_vector_type(8))) short bfx8;
typedef __attribute__((ext_vector_type(4))) short bfx4;
typedef __attribute__((ext_vector_type(4))) float f32x4;

__device__ __forceinline__ unsigned short f2bf(float x) {
  unsigned u = __float_as_uint(x);
  u += 0x7fffu + ((u >> 16) & 1u);
  return (unsigned short)(u >> 16);
}
__device__ __forceinline__ float bf2f(unsigned short u) {
  return __uint_as_float(((unsigned)u) << 16);
}
__device__ __forceinline__ void gload_lds16(const void* g, void* l) {
  __builtin_amdgcn_global_load_lds(
      (const __attribute__((address_space(1))) unsigned int*)g,
      (__attribute__((address_space(3))) unsigned int*)l, 16, 0, 0);
}

// ---------------- cast f32 -> bf16 (vectorized) ----------------
__global__ __launch_bounds__(256) void cast_bf16_kernel(
    const float* __restrict__ in, unsigned short* __restrict__ out, int n4) {
  int i = blockIdx.x * 256 + threadIdx.x;
  if (i >= n4) return;
  float4 v = ((const float4*)in)[i];
  bfx4 o;
  o[0] = (short)f2bf(v.x);
  o[1] = (short)f2bf(v.y);
  o[2] = (short)f2bf(v.z);
  o[3] = (short)f2bf(v.w);
  ((bfx4*)out)[i] = o;
}

// ---------------- GEMM: C[M,N] = A[M,K] * B[N,K]^T  (bf16 in, f32 acc) ----------------
// 128x128 tile, BK=64, 256 threads = 4 waves (2x2), each wave 64x64 via 4x4 MFMA 16x16x32.
template<bool BF16OUT>
__global__ __launch_bounds__(256) void gemm_bt_kernel(
    const unsigned short* __restrict__ A, const unsigned short* __restrict__ B,
    void* __restrict__ Cout, int M, int N, int K) {
  __shared__ unsigned short lA[128 * 64];
  __shared__ unsigned short lB[128 * 64];
  const int tid = threadIdx.x;
  const int w = tid >> 6, lane = tid & 63;
  const int g = lane >> 4, ln = lane & 15;
  const int bm = blockIdx.x * 128, bn = blockIdx.y * 128;
  const int wm = (w >> 1) * 64, wn = (w & 1) * 64;
  const int srow = lane >> 3;        // 0..7
  const int scol = (lane & 7) * 8;   // element col, multiple of 8 (16B)

  f32x4 acc[4][4];
#pragma unroll
  for (int i = 0; i < 4; ++i)
#pragma unroll
    for (int j = 0; j < 4; ++j) acc[i][j] = (f32x4){0.f, 0.f, 0.f, 0.f};

  for (int k0 = 0; k0 < K; k0 += 64) {
#pragma unroll
    for (int p = 0; p < 4; ++p) {
      int seg = p * 4 + w;            // 0..15, wave-uniform
      int row = seg * 8 + srow;       // 0..127
      const unsigned short* gA = A + (size_t)(bm + row) * K + (k0 + scol);
      const unsigned short* gB = B + (size_t)(bn + row) * K + (k0 + scol);
      gload_lds16(gA, lA + seg * 512);
      gload_lds16(gB, lB + seg * 512);
    }
    __syncthreads();
#pragma unroll
    for (int kk = 0; kk < 2; ++kk) {
      bfx8 af[4], bfr[4];
#pragma unroll
      for (int i = 0; i < 4; ++i)
        af[i] = *(const bfx8*)(lA + (wm + i * 16 + ln) * 64 + kk * 32 + g * 8);
#pragma unroll
      for (int j = 0; j < 4; ++j)
        bfr[j] = *(const bfx8*)(lB + (wn + j * 16 + ln) * 64 + kk * 32 + g * 8);
#pragma unroll
      for (int i = 0; i < 4; ++i)
#pragma unroll
        for (int j = 0; j < 4; ++j)
          acc[i][j] = __builtin_amdgcn_mfma_f32_16x16x32_bf16(af[i], bfr[j], acc[i][j], 0, 0, 0);
    }
    __syncthreads();
  }
  // epilogue: C row = bm+wm+i*16+g*4+r, col = bn+wn+j*16+ln
#pragma unroll
  for (int i = 0; i < 4; ++i) {
    int row0 = bm + wm + i * 16 + g * 4;
#pragma unroll
    for (int j = 0; j < 4; ++j) {
      int col = bn + wn + j * 16 + ln;
#pragma unroll
      for (int r = 0; r < 4; ++r) {
        if constexpr (BF16OUT)
          ((unsigned short*)Cout)[(size_t)(row0 + r) * N + col] = f2bf(acc[i][j][r]);
        else
          ((float*)Cout)[(size_t)(row0 + r) * N + col] = acc[i][j][r];
      }
    }
  }
}

// ---------------- RoPE + scatter: qkv[4096][6144] -> Q,K [BH][L][128], Vt [BH][128][L] ----------------
__global__ __launch_bounds__(256) void rope_scatter_kernel(
    const unsigned short* __restrict__ qkv,
    unsigned short* __restrict__ Qo, unsigned short* __restrict__ Ko,
    unsigned short* __restrict__ Vt) {
  __shared__ unsigned short lV[32 * 128];
  const int bh = blockIdx.x;           // b*16+h
  const int l0 = blockIdx.y * 32;
  const int b = bh >> 4, h = bh & 15;
  const int tid = threadIdx.x;
#pragma unroll
  for (int it = 0; it < 2; ++it) {
    int idx = it * 256 + tid;          // 0..511 = 32 l x 16 quads
    int ll = idx >> 4;                 // 0..31
    int dq = idx & 15;                 // quad: d2 = dq*4..+3
    int l = l0 + ll;
    const unsigned short* row = qkv + (size_t)(b * LSEQ + l) * NQKV + h * HD;
    bfx4 qlo = *(const bfx4*)(row + dq * 4);
    bfx4 qhi = *(const bfx4*)(row + 64 + dq * 4);
    bfx4 klo = *(const bfx4*)(row + 2048 + dq * 4);
    bfx4 khi = *(const bfx4*)(row + 2048 + 64 + dq * 4);
    bfx4 vlo = *(const bfx4*)(row + 4096 + dq * 4);
    bfx4 vhi = *(const bfx4*)(row + 4096 + 64 + dq * 4);
    bfx4 oqlo, oqhi, oklo, okhi;
#pragma unroll
    for (int e = 0; e < 4; ++e) {
      int d2 = dq * 4 + e;
      // inv_freq = 10000^(-d2/64) = exp2(-d2 * log2(10000)/64)
      float invf = exp2f(-(float)d2 * 0.2076205059304601f);
      float fr = (float)l * invf;
      float s, c;
      sincosf(fr, &s, &c);
      float xq1 = bf2f((unsigned short)qlo[e]), xq2 = bf2f((unsigned short)qhi[e]);
      oqlo[e] = (short)f2bf(xq1 * c - xq2 * s);
      oqhi[e] = (short)f2bf(xq2 * c + xq1 * s);
      float xk1 = bf2f((unsigned short)klo[e]), xk2 = bf2f((unsigned short)khi[e]);
      oklo[e] = (short)f2bf(xk1 * c - xk2 * s);
      okhi[e] = (short)f2bf(xk2 * c + xk1 * s);
    }
    size_t obase = ((size_t)bh * LSEQ + l) * HD;
    *(bfx4*)(Qo + obase + dq * 4) = oqlo;
    *(bfx4*)(Qo + obase + 64 + dq * 4) = oqhi;
    *(bfx4*)(Ko + obase + dq * 4) = oklo;
    *(bfx4*)(Ko + obase + 64 + dq * 4) = okhi;
    *(bfx4*)(lV + ll * 128 + dq * 4) = vlo;
    *(bfx4*)(lV + ll * 128 + 64 + dq * 4) = vhi;
  }
  __syncthreads();
#pragma unroll
  for (int it = 0; it < 16; ++it) {
    int idx = it * 256 + tid;          // 0..4095 = 128 d x 32 l
    int d = idx >> 5;
    int ll = idx & 31;
    Vt[((size_t)bh * HD + d) * LSEQ + l0 + ll] = lV[ll * 128 + d];
  }
}

// ---------------- Flash attention (causal), bf16 MFMA ----------------
// grid: (L/64, B*NH), 4 waves x 16 q-rows. S^T = mfma(K,Q): C col=q(ln), row=kv(4g+r).
__global__ __launch_bounds__(256) void flash_kernel(
    const unsigned short* __restrict__ Q, const unsigned short* __restrict__ K,
    const unsigned short* __restrict__ Vt, unsigned short* __restrict__ O) {
  __shared__ unsigned short Pt[4][16 * 32];  // per-wave P^T [q][kv]
  const int bh = blockIdx.y;
  const int q0 = blockIdx.x * 64;
  const int tid = threadIdx.x;
  const int w = tid >> 6, lane = tid & 63;
  const int g = lane >> 4, ln = lane & 15;
  const int q0w = q0 + w * 16;
  const unsigned short* Qb = Q + (size_t)bh * LSEQ * HD;
  const unsigned short* Kb = K + (size_t)bh * LSEQ * HD;
  const unsigned short* Vb = Vt + (size_t)bh * HD * LSEQ;
  unsigned short* Pw = Pt[w];

  bfx8 qf[4];
#pragma unroll
  for (int c = 0; c < 4; ++c)
    qf[c] = *(const bfx8*)(Qb + (size_t)(q0w + ln) * HD + c * 32 + g * 8);

  f32x4 o[8];
#pragma unroll
  for (int dt = 0; dt < 8; ++dt) o[dt] = (f32x4){0.f, 0.f, 0.f, 0.f};
  float m = -1e30f, sum = 0.f;
  const int qg = q0w + ln;
  const int nch = (q0w + 15) / 32 + 1;

  for (int ch = 0; ch < nch; ++ch) {
    int kv0 = ch * 32;
    f32x4 s0 = {0.f, 0.f, 0.f, 0.f}, s1 = {0.f, 0.f, 0.f, 0.f};
#pragma unroll
    for (int c = 0; c < 4; ++c) {
      bfx8 kf0 = *(const bfx8*)(Kb + (size_t)(kv0 + ln) * HD + c * 32 + g * 8);
      bfx8 kf1 = *(const bfx8*)(Kb + (size_t)(kv0 + 16 + ln) * HD + c * 32 + g * 8);
      s0 = __builtin_amdgcn_mfma_f32_16x16x32_bf16(kf0, qf[c], s0, 0, 0, 0);
      s1 = __builtin_amdgcn_mfma_f32_16x16x32_bf16(kf1, qf[c], s1, 0, 0, 0);
    }
    // mask + scale + tile max
    float tm = -1e30f;
#pragma unroll
    for (int r = 0; r < 4; ++r) {
      int kvr = kv0 + g * 4 + r;
      float v0 = (kvr <= qg) ? s0[r] * SCALE : -1e30f;
      float v1 = (kvr + 16 <= qg) ? s1[r] * SCALE : -1e30f;
      s0[r] = v0; s1[r] = v1;
      tm = fmaxf(tm, fmaxf(v0, v1));
    }
    tm = fmaxf(tm, __shfl_xor(tm, 16));
    tm = fmaxf(tm, __shfl_xor(tm, 32));
    float mnew = fmaxf(m, tm);
    float f = __expf(m - mnew);
    float ts = 0.f;
    unsigned short pb0[4], pb1[4];
#pragma unroll
    for (int r = 0; r < 4; ++r) {
      float p0 = __expf(s0[r] - mnew);
      float p1 = __expf(s1[r] - mnew);
      ts += p0 + p1;
      pb0[r] = f2bf(p0);
      pb1[r] = f2bf(p1);
    }
    ts += __shfl_xor(ts, 16);
    ts += __shfl_xor(ts, 32);
    sum = sum * f + ts;
    m = mnew;
    // P^T to LDS: Pt[q=ln][kv=16t+4g+r]
    bfx4 pk0 = {(short)pb0[0], (short)pb0[1], (short)pb0[2], (short)pb0[3]};
    bfx4 pk1 = {(short)pb1[0], (short)pb1[1], (short)pb1[2], (short)pb1[3]};
    *(bfx4*)(Pw + ln * 32 + 4 * g) = pk0;
    *(bfx4*)(Pw + ln * 32 + 16 + 4 * g) = pk1;
    asm volatile("s_waitcnt lgkmcnt(0)" ::: "memory");
    __builtin_amdgcn_sched_barrier(0);
    // per-output-row rescale factors (O rows are q=4g+r, state lives at lane q)
    float fr0 = __shfl(f, 4 * g + 0);
    float fr1 = __shfl(f, 4 * g + 1);
    float fr2 = __shfl(f, 4 * g + 2);
    float fr3 = __shfl(f, 4 * g + 3);
    bfx8 pf = *(const bfx8*)(Pw + ln * 32 + g * 8);  // A-frag: row=q(ln), k=kv(g*8+j)
#pragma unroll
    for (int dt = 0; dt < 8; ++dt) {
      o[dt][0] *= fr0; o[dt][1] *= fr1; o[dt][2] *= fr2; o[dt][3] *= fr3;
      bfx8 vf = *(const bfx8*)(Vb + (size_t)(dt * 16 + ln) * LSEQ + kv0 + g * 8);
      o[dt] = __builtin_amdgcn_mfma_f32_16x16x32_bf16(pf, vf, o[dt], 0, 0, 0);
    }
  }
  float inv = 1.f / sum;
  float ir0 = __shfl(inv, 4 * g + 0);
  float ir1 = __shfl(inv, 4 * g + 1);
  float ir2 = __shfl(inv, 4 * g + 2);
  float ir3 = __shfl(inv, 4 * g + 3);
  const int b = bh >> 4, h = bh & 15;
  unsigned short* Ob = O + (size_t)b * LSEQ * HDIM + h * HD;
#pragma unroll
  for (int dt = 0; dt < 8; ++dt) {
    Ob[(size_t)(q0w + 4 * g + 0) * HDIM + dt * 16 + ln] = f2bf(o[dt][0] * ir0);
    Ob[(size_t)(q0w + 4 * g + 1) * HDIM + dt * 16 + ln] = f2bf(o[dt][1] * ir1);
    Ob[(size_t)(q0w + 4 * g + 2) * HDIM + dt * 16 + ln] = f2bf(o[dt][2] * ir2);
    Ob[(size_t)(q0w + 4 * g + 3) * HDIM + dt * 16 + ln] = f2bf(o[dt][3] * ir3);
  }
}

// ---------------- launch ----------------
extern "C" void kernel_launch(void* const* d_in, const int* in_sizes, int n_in,
                              void* d_out, int out_size, void* d_ws, size_t ws_size,
                              hipStream_t stream) {
  const float* x = (const float*)d_in[0];       // [2,2048,2048]
  const float* w_qkv = (const float*)d_in[1];   // [6144,2048]
  const float* w_o = (const float*)d_in[2];     // [2048,2048]
  float* out = (float*)d_out;                   // [2,2048,2048] f32
  char* ws = (char*)d_ws;

  unsigned short* xb    = (unsigned short*)(ws + 0);           // 16.8 MB
  unsigned short* wqkvb = (unsigned short*)(ws + 16777216);    // 25.2 MB
  unsigned short* wob   = (unsigned short*)(ws + 41943040);    // 8.4 MB
  unsigned short* qkvb  = (unsigned short*)(ws + 50331648);    // 50.3 MB
  unsigned short* qb    = (unsigned short*)(ws + 100663296);   // 16.8 MB
  unsigned short* kb    = (unsigned short*)(ws + 117440512);   // 16.8 MB
  unsigned short* vtb   = (unsigned short*)(ws + 134217728);   // 16.8 MB
  unsigned short* attnb = (unsigned short*)(ws + 0);           // reuse x region

  cast_bf16_kernel<<<8388608 / 4 / 256, 256, 0, stream>>>(x, xb, 8388608 / 4);
  cast_bf16_kernel<<<12582912 / 4 / 256, 256, 0, stream>>>(w_qkv, wqkvb, 12582912 / 4);
  cast_bf16_kernel<<<4194304 / 4 / 256, 256, 0, stream>>>(w_o, wob, 4194304 / 4);

  gemm_bt_kernel<true><<<dim3(4096 / 128, 6144 / 128), 256, 0, stream>>>(
      xb, wqkvb, (void*)qkvb, 4096, 6144, 2048);

  rope_scatter_kernel<<<dim3(32, 64), 256, 0, stream>>>(qkvb, qb, kb, vtb);

  flash_kernel<<<dim3(32, 32), 256, 0, stream>>>(qb, kb, vtb, attnb);

  gemm_bt_kernel<false><<<dim3(4096 / 128, 2048 / 128), 256, 0, stream>>>(
      attnb, wob, (void*)out, 4096, 2048, 2048);
}

// Round 3
// 314.284 us; speedup vs baseline: 2.1878x; 2.1878x over previous
//
#include <hip/hip_runtime.h>

#define NHEADS 16
#define HD 128
#define LSEQ 2048
#define NBATCH 2
#define HDIM 2048
#define NQKV 6144
#define SCALE 0.08838834764831845f

typedef __attribute__((ext_vector_type(8))) short bfx8;
typedef __attribute__((ext_vector_type(4))) short bfx4;
typedef __attribute__((ext_vector_type(4))) float f32x4;

__device__ __forceinline__ unsigned short f2bf(float x) {
  unsigned u = __float_as_uint(x);
  u += 0x7fffu + ((u >> 16) & 1u);
  return (unsigned short)(u >> 16);
}
__device__ __forceinline__ float bf2f(unsigned short u) {
  return __uint_as_float(((unsigned)u) << 16);
}
__device__ __forceinline__ void gload_lds16(const void* g, void* l) {
  __builtin_amdgcn_global_load_lds(
      (const __attribute__((address_space(1))) unsigned int*)g,
      (__attribute__((address_space(3))) unsigned int*)l, 16, 0, 0);
}

// ---------------- cast f32 -> bf16 (vectorized) ----------------
__global__ __launch_bounds__(256) void cast_bf16_kernel(
    const float* __restrict__ in, unsigned short* __restrict__ out, int n4) {
  int i = blockIdx.x * 256 + threadIdx.x;
  if (i >= n4) return;
  float4 v = ((const float4*)in)[i];
  bfx4 o;
  o[0] = (short)f2bf(v.x);
  o[1] = (short)f2bf(v.y);
  o[2] = (short)f2bf(v.z);
  o[3] = (short)f2bf(v.w);
  ((bfx4*)out)[i] = o;
}

// ---------------- GEMM: C[M,N] = A[M,K] * B[N,K]^T  (bf16 in, f32 acc) ----------------
template<bool BF16OUT>
__global__ __launch_bounds__(256) void gemm_bt_kernel(
    const unsigned short* __restrict__ A, const unsigned short* __restrict__ B,
    void* __restrict__ Cout, int M, int N, int K) {
  __shared__ unsigned short lA[128 * 64];
  __shared__ unsigned short lB[128 * 64];
  const int tid = threadIdx.x;
  const int w = tid >> 6, lane = tid & 63;
  const int g = lane >> 4, ln = lane & 15;
  const int bm = blockIdx.x * 128, bn = blockIdx.y * 128;
  const int wm = (w >> 1) * 64, wn = (w & 1) * 64;
  const int srow = lane >> 3;
  const int scol = (lane & 7) * 8;

  f32x4 acc[4][4];
#pragma unroll
  for (int i = 0; i < 4; ++i)
#pragma unroll
    for (int j = 0; j < 4; ++j) acc[i][j] = (f32x4){0.f, 0.f, 0.f, 0.f};

  for (int k0 = 0; k0 < K; k0 += 64) {
#pragma unroll
    for (int p = 0; p < 4; ++p) {
      int seg = p * 4 + w;
      int row = seg * 8 + srow;
      const unsigned short* gA = A + (size_t)(bm + row) * K + (k0 + scol);
      const unsigned short* gB = B + (size_t)(bn + row) * K + (k0 + scol);
      gload_lds16(gA, lA + seg * 512);
      gload_lds16(gB, lB + seg * 512);
    }
    __syncthreads();
#pragma unroll
    for (int kk = 0; kk < 2; ++kk) {
      bfx8 af[4], bfr[4];
#pragma unroll
      for (int i = 0; i < 4; ++i)
        af[i] = *(const bfx8*)(lA + (wm + i * 16 + ln) * 64 + kk * 32 + g * 8);
#pragma unroll
      for (int j = 0; j < 4; ++j)
        bfr[j] = *(const bfx8*)(lB + (wn + j * 16 + ln) * 64 + kk * 32 + g * 8);
#pragma unroll
      for (int i = 0; i < 4; ++i)
#pragma unroll
        for (int j = 0; j < 4; ++j)
          acc[i][j] = __builtin_amdgcn_mfma_f32_16x16x32_bf16(af[i], bfr[j], acc[i][j], 0, 0, 0);
    }
    __syncthreads();
  }
#pragma unroll
  for (int i = 0; i < 4; ++i) {
    int row0 = bm + wm + i * 16 + g * 4;
#pragma unroll
    for (int j = 0; j < 4; ++j) {
      int col = bn + wn + j * 16 + ln;
#pragma unroll
      for (int r = 0; r < 4; ++r) {
        if constexpr (BF16OUT)
          ((unsigned short*)Cout)[(size_t)(row0 + r) * N + col] = f2bf(acc[i][j][r]);
        else
          ((float*)Cout)[(size_t)(row0 + r) * N + col] = acc[i][j][r];
      }
    }
  }
}

// ---------------- RoPE + scatter ----------------
__global__ __launch_bounds__(256) void rope_scatter_kernel(
    const unsigned short* __restrict__ qkv,
    unsigned short* __restrict__ Qo, unsigned short* __restrict__ Ko,
    unsigned short* __restrict__ Vt) {
  __shared__ unsigned short lV[32 * 128];
  const int bh = blockIdx.x;
  const int l0 = blockIdx.y * 32;
  const int b = bh >> 4, h = bh & 15;
  const int tid = threadIdx.x;
#pragma unroll
  for (int it = 0; it < 2; ++it) {
    int idx = it * 256 + tid;
    int ll = idx >> 4;
    int dq = idx & 15;
    int l = l0 + ll;
    const unsigned short* row = qkv + (size_t)(b * LSEQ + l) * NQKV + h * HD;
    bfx4 qlo = *(const bfx4*)(row + dq * 4);
    bfx4 qhi = *(const bfx4*)(row + 64 + dq * 4);
    bfx4 klo = *(const bfx4*)(row + 2048 + dq * 4);
    bfx4 khi = *(const bfx4*)(row + 2048 + 64 + dq * 4);
    bfx4 vlo = *(const bfx4*)(row + 4096 + dq * 4);
    bfx4 vhi = *(const bfx4*)(row + 4096 + 64 + dq * 4);
    bfx4 oqlo, oqhi, oklo, okhi;
#pragma unroll
    for (int e = 0; e < 4; ++e) {
      int d2 = dq * 4 + e;
      float invf = exp2f(-(float)d2 * 0.2076205059304601f);
      float fr = (float)l * invf;
      float s, c;
      sincosf(fr, &s, &c);
      float xq1 = bf2f((unsigned short)qlo[e]), xq2 = bf2f((unsigned short)qhi[e]);
      oqlo[e] = (short)f2bf(xq1 * c - xq2 * s);
      oqhi[e] = (short)f2bf(xq2 * c + xq1 * s);
      float xk1 = bf2f((unsigned short)klo[e]), xk2 = bf2f((unsigned short)khi[e]);
      oklo[e] = (short)f2bf(xk1 * c - xk2 * s);
      okhi[e] = (short)f2bf(xk2 * c + xk1 * s);
    }
    size_t obase = ((size_t)bh * LSEQ + l) * HD;
    *(bfx4*)(Qo + obase + dq * 4) = oqlo;
    *(bfx4*)(Qo + obase + 64 + dq * 4) = oqhi;
    *(bfx4*)(Ko + obase + dq * 4) = oklo;
    *(bfx4*)(Ko + obase + 64 + dq * 4) = okhi;
    *(bfx4*)(lV + ll * 128 + dq * 4) = vlo;
    *(bfx4*)(lV + ll * 128 + 64 + dq * 4) = vhi;
  }
  __syncthreads();
#pragma unroll
  for (int it = 0; it < 16; ++it) {
    int idx = it * 256 + tid;
    int d = idx >> 5;
    int ll = idx & 31;
    Vt[((size_t)bh * HD + d) * LSEQ + l0 + ll] = lV[ll * 128 + d];
  }
}

// ---------------- Flash attention v2: 8 waves, q-tile 128, KV chunk 64, LDS-staged ----------------
// grid: (bh=32, qy=16). qt = 15-qy (heavy first); XCD = bh%8 keeps each bh's K/V L2-local.
// S^T = mfma(K,Q): C col=q(ln), row=kv(16*kt+4g+r).
__global__ __launch_bounds__(512, 4) void flash_kernel(
    const unsigned short* __restrict__ Q, const unsigned short* __restrict__ K,
    const unsigned short* __restrict__ Vt, unsigned short* __restrict__ O) {
  __shared__ unsigned short lKs[2][64 * 128];  // [kv][d], swizzled slot^=(row&15)
  __shared__ unsigned short lVs[2][128 * 64];  // [d][kv], swizzled slot^=(d&7)
  __shared__ unsigned short lP[8][16 * 40];    // per-wave P, 80B row stride
  const int bh = blockIdx.x;
  const int qt = 15 - (int)blockIdx.y;
  const int q0 = qt * 128;
  const int tid = threadIdx.x;
  const int w = tid >> 6, lane = tid & 63;
  const int g = lane >> 4, ln = lane & 15;
  const int q0w = q0 + w * 16;
  const unsigned short* Qb = Q + (size_t)bh * LSEQ * HD;
  const unsigned short* Kb = K + (size_t)bh * LSEQ * HD;
  const unsigned short* Vb = Vt + (size_t)bh * HD * LSEQ;
  unsigned short* Pw = lP[w];

  auto STAGE = [&](int buf, int kv0s) {
#pragma unroll
    for (int s = 0; s < 2; ++s) {
      int rl = s * 32 + w * 4 + (lane >> 4);   // kv row 0..63
      int slot = lane & 15;
      const unsigned short* src =
          Kb + (size_t)(kv0s + rl) * HD + ((slot ^ (rl & 15)) * 8);
      gload_lds16(src, &lKs[buf][(s * 8192 + w * 1024) / 2]);
    }
#pragma unroll
    for (int s = 0; s < 2; ++s) {
      int d = s * 64 + w * 8 + (lane >> 3);    // 0..127
      int slot = lane & 7;
      const unsigned short* src =
          Vb + (size_t)d * LSEQ + kv0s + ((slot ^ (d & 7)) * 8);
      gload_lds16(src, &lVs[buf][(s * 8192 + w * 1024) / 2]);
    }
  };

  bfx8 qf[4];
#pragma unroll
  for (int c = 0; c < 4; ++c)
    qf[c] = *(const bfx8*)(Qb + (size_t)(q0w + ln) * HD + c * 32 + g * 8);

  f32x4 o[8];
#pragma unroll
  for (int dt = 0; dt < 8; ++dt) o[dt] = (f32x4){0.f, 0.f, 0.f, 0.f};
  float m = -1e30f, sum = 0.f;
  const int qg = q0w + ln;
  const int nch = 2 * qt + 2;

  STAGE(0, 0);
  __syncthreads();

  for (int ch = 0; ch < nch; ++ch) {
    const int kv0 = ch * 64;
    const int cur = ch & 1;
    if (ch + 1 < nch) STAGE(cur ^ 1, kv0 + 64);

    if (kv0 <= q0w + 15) {
      const char* lK0 = (const char*)lKs[cur];
      const char* lV0 = (const char*)lVs[cur];
      // --- QK^T ---
      f32x4 s4[4];
#pragma unroll
      for (int kt = 0; kt < 4; ++kt) s4[kt] = (f32x4){0.f, 0.f, 0.f, 0.f};
#pragma unroll
      for (int c = 0; c < 4; ++c) {
        const int cbb = c * 64 + g * 16;
#pragma unroll
        for (int kt = 0; kt < 4; ++kt) {
          bfx8 kf = *(const bfx8*)(lK0 + (kt * 16 + ln) * 256 + (cbb ^ (ln << 4)));
          s4[kt] = __builtin_amdgcn_mfma_f32_16x16x32_bf16(kf, qf[c], s4[kt], 0, 0, 0);
        }
      }
      // --- scale + mask + tile max ---
      float tm = -1e30f;
      if (kv0 + 63 <= q0w) {
#pragma unroll
        for (int kt = 0; kt < 4; ++kt)
#pragma unroll
          for (int r = 0; r < 4; ++r) {
            s4[kt][r] *= SCALE;
            tm = fmaxf(tm, s4[kt][r]);
          }
      } else {
#pragma unroll
        for (int kt = 0; kt < 4; ++kt)
#pragma unroll
          for (int r = 0; r < 4; ++r) {
            int kvr = kv0 + kt * 16 + 4 * g + r;
            float v = (kvr <= qg) ? s4[kt][r] * SCALE : -1e30f;
            s4[kt][r] = v;
            tm = fmaxf(tm, v);
          }
      }
      tm = fmaxf(tm, __shfl_xor(tm, 16));
      tm = fmaxf(tm, __shfl_xor(tm, 32));
      // --- defer-max (T13) ---
      float f = 1.f;
      const bool dorescale = !__all(tm <= m + 8.f);
      if (dorescale) {
        float mnew = fmaxf(m, tm);
        f = __expf(m - mnew);
        m = mnew;
      }
      // --- exp + row-sum ---
      float ts = 0.f;
      bfx4 pb4[4];
#pragma unroll
      for (int kt = 0; kt < 4; ++kt)
#pragma unroll
        for (int r = 0; r < 4; ++r) {
          float p = __expf(s4[kt][r] - m);
          ts += p;
          pb4[kt][r] = (short)f2bf(p);
        }
      ts += __shfl_xor(ts, 16);
      ts += __shfl_xor(ts, 32);
      sum = sum * f + ts;
      float fr0 = 1.f, fr1 = 1.f, fr2 = 1.f, fr3 = 1.f;
      if (dorescale) {
        fr0 = __shfl(f, 4 * g + 0);
        fr1 = __shfl(f, 4 * g + 1);
        fr2 = __shfl(f, 4 * g + 2);
        fr3 = __shfl(f, 4 * g + 3);
      }
      // --- PV in two 32-kv halves ---
#pragma unroll
      for (int kvh = 0; kvh < 2; ++kvh) {
        asm volatile("s_waitcnt lgkmcnt(0)" ::: "memory");
        __builtin_amdgcn_sched_barrier(0);
        *(bfx4*)(Pw + ln * 40 + 4 * g) = pb4[2 * kvh];
        *(bfx4*)(Pw + ln * 40 + 16 + 4 * g) = pb4[2 * kvh + 1];
        asm volatile("s_waitcnt lgkmcnt(0)" ::: "memory");
        __builtin_amdgcn_sched_barrier(0);
        bfx8 pf = *(const bfx8*)(Pw + ln * 40 + g * 8);
        if (kvh == 0 && dorescale) {
#pragma unroll
          for (int dt = 0; dt < 8; ++dt) {
            o[dt][0] *= fr0; o[dt][1] *= fr1; o[dt][2] *= fr2; o[dt][3] *= fr3;
          }
        }
#pragma unroll
        for (int dt = 0; dt < 8; ++dt) {
          bfx8 vf = *(const bfx8*)(lV0 + (dt * 16 + ln) * 128 +
                                   ((kvh * 64 + g * 16) ^ ((ln & 7) << 4)));
          o[dt] = __builtin_amdgcn_mfma_f32_16x16x32_bf16(pf, vf, o[dt], 0, 0, 0);
        }
      }
    }
    __syncthreads();
  }

  float inv = 1.f / sum;
  float ir0 = __shfl(inv, 4 * g + 0);
  float ir1 = __shfl(inv, 4 * g + 1);
  float ir2 = __shfl(inv, 4 * g + 2);
  float ir3 = __shfl(inv, 4 * g + 3);
  const int b = bh >> 4, h = bh & 15;
  unsigned short* Ob = O + (size_t)b * LSEQ * HDIM + h * HD;
#pragma unroll
  for (int dt = 0; dt < 8; ++dt) {
    Ob[(size_t)(q0w + 4 * g + 0) * HDIM + dt * 16 + ln] = f2bf(o[dt][0] * ir0);
    Ob[(size_t)(q0w + 4 * g + 1) * HDIM + dt * 16 + ln] = f2bf(o[dt][1] * ir1);
    Ob[(size_t)(q0w + 4 * g + 2) * HDIM + dt * 16 + ln] = f2bf(o[dt][2] * ir2);
    Ob[(size_t)(q0w + 4 * g + 3) * HDIM + dt * 16 + ln] = f2bf(o[dt][3] * ir3);
  }
}

// ---------------- launch ----------------
extern "C" void kernel_launch(void* const* d_in, const int* in_sizes, int n_in,
                              void* d_out, int out_size, void* d_ws, size_t ws_size,
                              hipStream_t stream) {
  const float* x = (const float*)d_in[0];
  const float* w_qkv = (const float*)d_in[1];
  const float* w_o = (const float*)d_in[2];
  float* out = (float*)d_out;
  char* ws = (char*)d_ws;

  unsigned short* xb    = (unsigned short*)(ws + 0);
  unsigned short* wqkvb = (unsigned short*)(ws + 16777216);
  unsigned short* wob   = (unsigned short*)(ws + 41943040);
  unsigned short* qkvb  = (unsigned short*)(ws + 50331648);
  unsigned short* qb    = (unsigned short*)(ws + 100663296);
  unsigned short* kb    = (unsigned short*)(ws + 117440512);
  unsigned short* vtb   = (unsigned short*)(ws + 134217728);
  unsigned short* attnb = (unsigned short*)(ws + 0);

  cast_bf16_kernel<<<8388608 / 4 / 256, 256, 0, stream>>>(x, xb, 8388608 / 4);
  cast_bf16_kernel<<<12582912 / 4 / 256, 256, 0, stream>>>(w_qkv, wqkvb, 12582912 / 4);
  cast_bf16_kernel<<<4194304 / 4 / 256, 256, 0, stream>>>(w_o, wob, 4194304 / 4);

  gemm_bt_kernel<true><<<dim3(4096 / 128, 6144 / 128), 256, 0, stream>>>(
      xb, wqkvb, (void*)qkvb, 4096, 6144, 2048);

  rope_scatter_kernel<<<dim3(32, 64), 256, 0, stream>>>(qkvb, qb, kb, vtb);

  flash_kernel<<<dim3(32, 16), 512, 0, stream>>>(qb, kb, vtb, attnb);

  gemm_bt_kernel<false><<<dim3(4096 / 128, 2048 / 128), 256, 0, stream>>>(
      attnb, wob, (void*)out, 4096, 2048, 2048);
}